// Round 1
// baseline (199.875 us; speedup 1.0000x reference)
//
#include <hip/hip_runtime.h>
#include <hip/hip_bf16.h>

// CumulativeLayerNorm: x [B=8, C=512, T=16000] f32.
// Pass 1: per-(b,t) column sums s1=Σ_c x, q=Σ_c x².
// Pass 2: per-b scan over t: mean, istd.
// Pass 3: normalize.
// Workspace layout (floats): s1[B*T], q[B*T], mean[B*T], istd[B*T]  (~2 MB).

constexpr int Bb = 8;
constexpr int Cc = 512;
constexpr int Tt = 16000;
constexpr float EPSF = 1e-8f;

// ---------------- Pass 1: column stats ----------------
__global__ __launch_bounds__(256)
void colstats_kernel(const float* __restrict__ x,
                     float* __restrict__ s1g, float* __restrict__ qg)
{
    int t = blockIdx.x * blockDim.x + threadIdx.x;
    int b = blockIdx.y;
    if (t >= Tt) return;
    const float* xb = x + (size_t)b * Cc * Tt + t;

    float a[8] = {0.f,0.f,0.f,0.f,0.f,0.f,0.f,0.f};
    float qq[8] = {0.f,0.f,0.f,0.f,0.f,0.f,0.f,0.f};
    #pragma unroll 1
    for (int c = 0; c < Cc; c += 8) {
        #pragma unroll
        for (int u = 0; u < 8; ++u) {
            float v = xb[(size_t)(c + u) * Tt];
            a[u] += v;
            qq[u] += v * v;
        }
    }
    float s = ((a[0]+a[1])+(a[2]+a[3])) + ((a[4]+a[5])+(a[6]+a[7]));
    float q = ((qq[0]+qq[1])+(qq[2]+qq[3])) + ((qq[4]+qq[5])+(qq[6]+qq[7]));
    s1g[b * Tt + t] = s;
    qg[b * Tt + t]  = q;
}

// ---------------- Pass 2: per-batch cumulative scan ----------------
#define SCAN_THREADS 1024
#define NWAVES (SCAN_THREADS / 64)

__global__ __launch_bounds__(SCAN_THREADS)
void scan_kernel(const float* __restrict__ s1g, const float* __restrict__ qg,
                 float* __restrict__ meang, float* __restrict__ istdg)
{
    __shared__ float lds[NWAVES];
    const int b = blockIdx.x;
    const int tid = threadIdx.x;
    const int lane = tid & 63;
    const int wave = tid >> 6;

    const float* s1 = s1g + (size_t)b * Tt;
    const float* q  = qg  + (size_t)b * Tt;
    float* mean = meang + (size_t)b * Tt;
    float* istd = istdg + (size_t)b * Tt;

    const float Cf = (float)Cc;
    float carry1 = 0.f, carry2 = 0.f;
    const int nchunks = (Tt + SCAN_THREADS - 1) / SCAN_THREADS;

    for (int ch = 0; ch < nchunks; ++ch) {
        const int t = ch * SCAN_THREADS + tid;
        const bool valid = (t < Tt);
        float v1 = valid ? s1[t] : 0.f;
        float vq = valid ? q[t]  : 0.f;

        // --- inclusive scan of v1 ---
        float sc = v1;
        #pragma unroll
        for (int off = 1; off < 64; off <<= 1) {
            float n = __shfl_up(sc, off, 64);
            if (lane >= off) sc += n;
        }
        __syncthreads();                 // lds safe to overwrite
        if (lane == 63) lds[wave] = sc;
        __syncthreads();
        float pre = 0.f, tot = 0.f;
        #pragma unroll
        for (int w = 0; w < NWAVES; ++w) {
            float val = lds[w];
            if (w < wave) pre += val;
            tot += val;
        }
        const float cs1 = sc + pre + carry1;
        carry1 += tot;

        const float cnt = Cf * (float)(t + 1);
        const float mn = cs1 / cnt;
        // residual second moment at this t (0 for invalid lanes so scan is clean)
        const float s2 = valid ? (vq - 2.f * mn * v1 + Cf * mn * mn) : 0.f;

        // --- inclusive scan of s2 ---
        float sc2 = s2;
        #pragma unroll
        for (int off = 1; off < 64; off <<= 1) {
            float n = __shfl_up(sc2, off, 64);
            if (lane >= off) sc2 += n;
        }
        __syncthreads();
        if (lane == 63) lds[wave] = sc2;
        __syncthreads();
        float pre2 = 0.f, tot2 = 0.f;
        #pragma unroll
        for (int w = 0; w < NWAVES; ++w) {
            float val = lds[w];
            if (w < wave) pre2 += val;
            tot2 += val;
        }
        const float cvar = sc2 + pre2 + carry2;
        carry2 += tot2;

        if (valid) {
            mean[t] = mn;
            const float var = cvar / cnt;
            istd[t] = rsqrtf(var + EPSF);
        }
    }
}

// ---------------- Pass 3: normalize ----------------
__global__ __launch_bounds__(256)
void normalize_kernel(const float4* __restrict__ x4,
                      const float* __restrict__ meang,
                      const float* __restrict__ istdg,
                      const float* __restrict__ gamma,
                      const float* __restrict__ beta,
                      float4* __restrict__ out4)
{
    constexpr int T4 = Tt / 4;                 // 4000
    constexpr long long n4 = (long long)Bb * Cc * T4;
    long long i = (long long)blockIdx.x * blockDim.x + threadIdx.x;
    const long long stride = (long long)gridDim.x * blockDim.x;

    for (; i < n4; i += stride) {
        const int t4 = (int)(i % T4);
        const int bc = (int)(i / T4);
        const int c = bc & (Cc - 1);
        const int b = bc >> 9;                 // Cc = 512 = 2^9

        const float4 xv = x4[i];
        const float4 m4 = *reinterpret_cast<const float4*>(meang + (size_t)b * Tt + t4 * 4);
        const float4 s4 = *reinterpret_cast<const float4*>(istdg + (size_t)b * Tt + t4 * 4);
        const float g = gamma[c];
        const float be = beta[c];

        float4 o;
        o.x = (xv.x - m4.x) * s4.x * g + be;
        o.y = (xv.y - m4.y) * s4.y * g + be;
        o.z = (xv.z - m4.z) * s4.z * g + be;
        o.w = (xv.w - m4.w) * s4.w * g + be;
        out4[i] = o;
    }
}

extern "C" void kernel_launch(void* const* d_in, const int* in_sizes, int n_in,
                              void* d_out, int out_size, void* d_ws, size_t ws_size,
                              hipStream_t stream) {
    const float* x     = (const float*)d_in[0];
    const float* gamma = (const float*)d_in[1];
    const float* beta  = (const float*)d_in[2];
    float* out = (float*)d_out;

    float* ws   = (float*)d_ws;
    float* s1   = ws;                       // B*T
    float* q    = ws + (size_t)Bb * Tt;     // B*T
    float* mean = ws + (size_t)2 * Bb * Tt; // B*T
    float* istd = ws + (size_t)3 * Bb * Tt; // B*T

    // Pass 1: column stats
    dim3 g1((Tt + 255) / 256, Bb);
    colstats_kernel<<<g1, 256, 0, stream>>>(x, s1, q);

    // Pass 2: scan (one block per batch)
    scan_kernel<<<Bb, SCAN_THREADS, 0, stream>>>(s1, q, mean, istd);

    // Pass 3: normalize
    normalize_kernel<<<4096, 256, 0, stream>>>(
        (const float4*)x, mean, istd, gamma, beta, (float4*)out);
}

// Round 2
// 131.980 us; speedup vs baseline: 1.5144x; 1.5144x over previous
//
#include <hip/hip_runtime.h>
#include <hip/hip_bf16.h>

// CumulativeLayerNorm: x [B=8, C=512, T=16000] f32.
// Pass 1: per-(b,t) column sums s1=Σ_c x, q=Σ_c x² (C split in 2 chunks for TLP).
// Pass 2: per-b hierarchical scan over t (thread-serial 16 elems/thread): mean, istd.
// Pass 3: normalize, REVERSE traversal (L3 reuse of x) + nontemporal out stores.
// Workspace (floats): s1p[2*B*T], qp[2*B*T], mean[B*T], istd[B*T]  (~3.1 MB).

constexpr int Bb = 8;
constexpr int Cc = 512;
constexpr int Tt = 16000;
constexpr int T4 = Tt / 4;      // 4000
constexpr int NCH = 2;          // c-chunks in pass 1
constexpr int CPC = Cc / NCH;   // 256
constexpr float EPSF = 1e-8f;

typedef float f32x4 __attribute__((ext_vector_type(4)));

// ---------------- Pass 1: column stats (float4 over t) ----------------
__global__ __launch_bounds__(256)
void colstats_kernel(const float* __restrict__ x,
                     float* __restrict__ s1p, float* __restrict__ qp)
{
    const int t4 = blockIdx.x * 256 + threadIdx.x;
    const int b  = blockIdx.y;
    const int ch = blockIdx.z;
    if (t4 >= T4) return;

    const f32x4* xb = (const f32x4*)x + (size_t)(b * Cc + ch * CPC) * T4 + t4;

    f32x4 as0 = 0, as1 = 0, as2 = 0, as3 = 0;
    f32x4 aq0 = 0, aq1 = 0, aq2 = 0, aq3 = 0;

    #pragma unroll 1
    for (int c = 0; c < CPC; c += 16) {
        f32x4 v[16];
        #pragma unroll
        for (int u = 0; u < 16; ++u)
            v[u] = xb[(size_t)(c + u) * T4];
        #pragma unroll
        for (int u = 0; u < 16; u += 4) {
            as0 += v[u+0]; aq0 += v[u+0] * v[u+0];
            as1 += v[u+1]; aq1 += v[u+1] * v[u+1];
            as2 += v[u+2]; aq2 += v[u+2] * v[u+2];
            as3 += v[u+3]; aq3 += v[u+3] * v[u+3];
        }
    }
    f32x4 s = (as0 + as1) + (as2 + as3);
    f32x4 q = (aq0 + aq1) + (aq2 + aq3);

    const int oidx = (ch * Bb + b) * T4 + t4;
    ((f32x4*)s1p)[oidx] = s;
    ((f32x4*)qp)[oidx]  = q;
}

// ---------------- Pass 2: per-batch scan, thread-serial 16/thread ----------------
#define SCAN_THREADS 1024

__device__ __forceinline__ float block_exscan(float val, int lane, int wave, float* lds)
{
    float sc = val;
    #pragma unroll
    for (int off = 1; off < 64; off <<= 1) {
        float n = __shfl_up(sc, off, 64);
        if (lane >= off) sc += n;
    }
    __syncthreads();                 // lds safe to overwrite (reuse across calls)
    if (lane == 63) lds[wave] = sc;
    __syncthreads();
    float pre = 0.f;
    #pragma unroll
    for (int w = 0; w < SCAN_THREADS / 64; ++w)
        if (w < wave) pre += lds[w];
    return pre + sc - val;           // exclusive prefix of this thread's val
}

__global__ __launch_bounds__(SCAN_THREADS)
void scan_kernel(const float* __restrict__ s1p, const float* __restrict__ qp,
                 float* __restrict__ meang, float* __restrict__ istdg)
{
    __shared__ float lds[SCAN_THREADS / 64];
    const int b    = blockIdx.x;
    const int tid  = threadIdx.x;
    const int lane = tid & 63;
    const int wave = tid >> 6;
    const float Cf = (float)Cc;

    const bool valid = tid < (Tt / 16);   // 1000 threads exactly cover T

    float s1v[16], qv[16];
    if (valid) {
        #pragma unroll
        for (int g = 0; g < 4; ++g) {
            f32x4 a = 0, qq = 0;
            #pragma unroll
            for (int ch = 0; ch < NCH; ++ch) {
                const int idx = (ch * Bb + b) * T4 + tid * 4 + g;
                a  += ((const f32x4*)s1p)[idx];
                qq += ((const f32x4*)qp)[idx];
            }
            s1v[4*g+0] = a.x; s1v[4*g+1] = a.y; s1v[4*g+2] = a.z; s1v[4*g+3] = a.w;
            qv[4*g+0] = qq.x; qv[4*g+1] = qq.y; qv[4*g+2] = qq.z; qv[4*g+3] = qq.w;
        }
    } else {
        #pragma unroll
        for (int i = 0; i < 16; ++i) { s1v[i] = 0.f; qv[i] = 0.f; }
    }

    // ---- scan of s1 ----
    float lsum = 0.f;
    #pragma unroll
    for (int i = 0; i < 16; ++i) lsum += s1v[i];
    const float base1 = block_exscan(lsum, lane, wave, lds);

    // serial walk: mean per element, s2 per element (stored into qv)
    float mean_r[16];
    float l2 = 0.f;
    {
        float cs = base1;
        #pragma unroll
        for (int i = 0; i < 16; ++i) {
            cs += s1v[i];
            const int t = tid * 16 + i;
            const float cnt = Cf * (float)(t + 1);
            const float mn = cs / cnt;
            mean_r[i] = mn;
            const float s2 = qv[i] - 2.f * mn * s1v[i] + Cf * mn * mn;
            qv[i] = s2;
            l2 += s2;
        }
    }
    if (!valid) l2 = 0.f;

    // ---- scan of s2 ----
    const float base2 = block_exscan(l2, lane, wave, lds);

    if (valid) {
        float cv = base2;
        float istd_r[16];
        #pragma unroll
        for (int i = 0; i < 16; ++i) {
            cv += (tid < (Tt/16)) ? qv[i] : 0.f;
            const int t = tid * 16 + i;
            const float cnt = Cf * (float)(t + 1);
            const float var = cv / cnt;
            istd_r[i] = rsqrtf(var + EPSF);
        }
        f32x4* mo = (f32x4*)(meang + (size_t)b * Tt) + tid * 4;
        f32x4* io = (f32x4*)(istdg + (size_t)b * Tt) + tid * 4;
        #pragma unroll
        for (int g = 0; g < 4; ++g) {
            f32x4 m, s;
            m.x = mean_r[4*g+0]; m.y = mean_r[4*g+1]; m.z = mean_r[4*g+2]; m.w = mean_r[4*g+3];
            s.x = istd_r[4*g+0]; s.y = istd_r[4*g+1]; s.z = istd_r[4*g+2]; s.w = istd_r[4*g+3];
            mo[g] = m;
            io[g] = s;
        }
    }
}

// ---------------- Pass 3: normalize (reverse order, nt stores) ----------------
__global__ __launch_bounds__(256)
void normalize_kernel(const f32x4* __restrict__ x4,
                      const float* __restrict__ meang,
                      const float* __restrict__ istdg,
                      const float* __restrict__ gamma,
                      const float* __restrict__ beta,
                      f32x4* __restrict__ out4)
{
    constexpr int n4 = Bb * Cc * T4;           // 16,384,000 (fits int)
    const int gtid   = blockIdx.x * 256 + threadIdx.x;
    const int stride = gridDim.x * 256;
    const int nloop  = (n4 + stride - 1) / stride;

    // Reverse sweep: pass 1 just streamed x forward, so the TAIL of x is
    // L3-resident. Reading backward turns the re-read into L3 hits instead
    // of LRU cyclic thrash. Non-temporal out stores keep x resident.
    for (int k = nloop - 1; k >= 0; --k) {
        const int i = k * stride + gtid;
        if (i >= n4) continue;
        const int t4 = i % T4;
        const int bc = i / T4;
        const int c  = bc & (Cc - 1);
        const int b  = bc >> 9;                // Cc = 512 = 2^9

        const f32x4 xv = x4[i];
        const f32x4 m4 = *(const f32x4*)(meang + (size_t)b * Tt + t4 * 4);
        const f32x4 s4 = *(const f32x4*)(istdg + (size_t)b * Tt + t4 * 4);
        const float g  = gamma[c];
        const float be = beta[c];

        const f32x4 o = (xv - m4) * s4 * g + be;
        __builtin_nontemporal_store(o, &out4[i]);
    }
}

extern "C" void kernel_launch(void* const* d_in, const int* in_sizes, int n_in,
                              void* d_out, int out_size, void* d_ws, size_t ws_size,
                              hipStream_t stream) {
    const float* x     = (const float*)d_in[0];
    const float* gamma = (const float*)d_in[1];
    const float* beta  = (const float*)d_in[2];
    float* out = (float*)d_out;

    float* ws   = (float*)d_ws;
    float* s1p  = ws;                                  // NCH*B*T
    float* qp   = ws + (size_t)NCH * Bb * Tt;          // NCH*B*T
    float* mean = ws + (size_t)2 * NCH * Bb * Tt;      // B*T
    float* istd = mean + (size_t)Bb * Tt;              // B*T

    // Pass 1: column stats
    dim3 g1((T4 + 255) / 256, Bb, NCH);
    colstats_kernel<<<g1, 256, 0, stream>>>(x, s1p, qp);

    // Pass 2: scan (one block per batch)
    scan_kernel<<<Bb, SCAN_THREADS, 0, stream>>>(s1p, qp, mean, istd);

    // Pass 3: normalize (reverse)
    normalize_kernel<<<4096, 256, 0, stream>>>(
        (const f32x4*)x, mean, istd, gamma, beta, (f32x4*)out);
}